// Round 1
// baseline (117.032 us; speedup 1.0000x reference)
//
#include <hip/hip_runtime.h>

#define BB 8
#define CC 128
#define HH 64
#define WW 64
#define OO 128
#define KT 9   // 3x3 taps

typedef __attribute__((ext_vector_type(8))) short short8;
typedef __attribute__((ext_vector_type(4))) float f32x4;

__device__ inline unsigned short f2bf(float f) {
    union { float f; unsigned int u; } x; x.f = f;
    unsigned int u = x.u;
    unsigned int r = u + 0x7fff + ((u >> 16) & 1);
    return (unsigned short)(r >> 16);
}

// ---- prep 1: NCHW -> NHWC (per-b 128 x 4096 transpose) ----
__global__ __launch_bounds__(256) void transpose_nchw_nhwc(
    const float* __restrict__ in, float* __restrict__ out) {
    __shared__ float t[32][33];
    int b  = blockIdx.z;
    int c0 = blockIdx.y * 32;
    int s0 = blockIdx.x * 32;
    int tx = threadIdx.x & 31;
    int ty = threadIdx.x >> 5;  // 0..7
    const float* ip = in + (size_t)b * CC * HH * WW;
    float* op = out + (size_t)b * HH * WW * CC;
#pragma unroll
    for (int i = 0; i < 32; i += 8)
        t[ty + i][tx] = ip[(size_t)(c0 + ty + i) * (HH * WW) + s0 + tx];
    __syncthreads();
#pragma unroll
    for (int i = 0; i < 32; i += 8)
        op[(size_t)(s0 + ty + i) * CC + c0 + tx] = t[tx][ty + i];
}

// ---- prep 2: weight (O,C,3,3) fp32 -> wbf[k][o][c] bf16 ----
__global__ __launch_bounds__(256) void prep_weight(
    const float* __restrict__ w, unsigned short* __restrict__ wbf) {
    int i = blockIdx.x * 256 + threadIdx.x;
    if (i >= KT * OO * CC) return;
    int k = i / (OO * CC);
    int r = i % (OO * CC);
    int o = r >> 7, c = r & 127;
    wbf[i] = f2bf(w[o * (CC * KT) + c * KT + k]);
}

// ---- main: per block = one (b, ho) row of 64 pixels x all 128 outputs ----
__global__ __launch_bounds__(256) void deform_main(
    const float* __restrict__ inhwc, const unsigned short* __restrict__ wbf,
    const float* __restrict__ offset, const float* __restrict__ mask,
    const float* __restrict__ bias, float* __restrict__ out) {
    __shared__ unsigned short Al[64 * 128];    // [pixel][c] bf16, XOR-swizzled
    __shared__ unsigned short Bl[128 * 128];   // [o][c] bf16, XOR-swizzled

    int bid = blockIdx.x;
    int b  = bid >> 6;
    int ho = bid & 63;
    int tid  = threadIdx.x;
    int wave = tid >> 6;
    int lane = tid & 63;
    int m_off = (wave >> 1) * 32;   // pixel tile offset
    int n_off = (wave & 1) * 64;    // o tile offset
    int lr = lane & 15;
    int lk = (lane >> 4) * 8;       // k-element offset within K=32

    f32x4 acc[2][4] = {};

    // sampling thread mapping: 4 threads per pixel, 32 channels each
    int sp = tid >> 2;
    int sc = (tid & 3) * 32;

    for (int k = 0; k < KT; ++k) {
        __syncthreads();  // previous iter's LDS reads done before overwrite

        // ---- stage B: wbf[k] (128x128 bf16) -> Bl
        {
            int o  = tid >> 1;
            int cb = (tid & 1) * 64;
            const int4* s4 = (const int4*)(wbf + (size_t)k * OO * CC + o * CC + cb);
#pragma unroll
            for (int j = 0; j < 8; ++j) {
                unsigned byte = (unsigned)(o * 256 + (cb + j * 8) * 2);
                byte ^= (unsigned)((o & 7) << 4);
                *(int4*)((char*)Bl + byte) = s4[j];
            }
        }

        // ---- stage A: bilinear-sample 64 pixels x 128 channels for tap k
        {
            int kh = k / 3, kw = k % 3;
            int wo = sp;
            float offy = offset[((size_t)(b * 18 + 2 * k) * 64 + ho) * 64 + wo];
            float offx = offset[((size_t)(b * 18 + 2 * k + 1) * 64 + ho) * 64 + wo];
            float mm   = mask[((size_t)(b * 9 + k) * 64 + ho) * 64 + wo];
            float py = (float)(ho - 1 + kh) + offy;
            float px = (float)(wo - 1 + kw) + offx;
            float fy = floorf(py), fx = floorf(px);
            float wy1 = py - fy, wx1 = px - fx;
            float wy0 = 1.f - wy1, wx0 = 1.f - wx1;
            int y0 = (int)fy, x0 = (int)fx;
            int y1 = y0 + 1, x1 = x0 + 1;
            bool vy0 = (y0 >= 0) & (y0 < HH);
            bool vy1 = (y1 >= 0) & (y1 < HH);
            bool vx0 = (x0 >= 0) & (x0 < WW);
            bool vx1 = (x1 >= 0) & (x1 < WW);
            float w00 = (vy0 & vx0) ? wy0 * wx0 * mm : 0.f;
            float w01 = (vy0 & vx1) ? wy0 * wx1 * mm : 0.f;
            float w10 = (vy1 & vx0) ? wy1 * wx0 * mm : 0.f;
            float w11 = (vy1 & vx1) ? wy1 * wx1 * mm : 0.f;
            int y0c = min(max(y0, 0), HH - 1), y1c = min(max(y1, 0), HH - 1);
            int x0c = min(max(x0, 0), WW - 1), x1c = min(max(x1, 0), WW - 1);
            const float* p00 = inhwc + ((size_t)(b * HH + y0c) * WW + x0c) * CC + sc;
            const float* p01 = inhwc + ((size_t)(b * HH + y0c) * WW + x1c) * CC + sc;
            const float* p10 = inhwc + ((size_t)(b * HH + y1c) * WW + x0c) * CC + sc;
            const float* p11 = inhwc + ((size_t)(b * HH + y1c) * WW + x1c) * CC + sc;
#pragma unroll
            for (int j = 0; j < 8; ++j) {
                float4 v00 = *(const float4*)(p00 + j * 4);
                float4 v01 = *(const float4*)(p01 + j * 4);
                float4 v10 = *(const float4*)(p10 + j * 4);
                float4 v11 = *(const float4*)(p11 + j * 4);
                float sx = w00 * v00.x + w01 * v01.x + w10 * v10.x + w11 * v11.x;
                float sy = w00 * v00.y + w01 * v01.y + w10 * v10.y + w11 * v11.y;
                float sz = w00 * v00.z + w01 * v01.z + w10 * v10.z + w11 * v11.z;
                float sw = w00 * v00.w + w01 * v01.w + w10 * v10.w + w11 * v11.w;
                ushort4 sb;
                sb.x = f2bf(sx); sb.y = f2bf(sy); sb.z = f2bf(sz); sb.w = f2bf(sw);
                unsigned byte = (unsigned)(sp * 256 + (sc + j * 4) * 2);
                byte ^= (unsigned)((sp & 7) << 4);
                *(ushort4*)((char*)Al + byte) = sb;
            }
        }
        __syncthreads();

        // ---- compute: 4 x (K=32) MFMA steps over this tap's 128 channels
#pragma unroll
        for (int c32 = 0; c32 < 4; ++c32) {
            short8 a[2];
            short8 bb[4];
#pragma unroll
            for (int i = 0; i < 2; ++i) {
                int row = m_off + i * 16 + lr;
                unsigned byte = (unsigned)(row * 256 + (c32 * 32 + lk) * 2);
                byte ^= (unsigned)((row & 7) << 4);
                a[i] = *(const short8*)((const char*)Al + byte);
            }
#pragma unroll
            for (int i = 0; i < 4; ++i) {
                int row = n_off + i * 16 + lr;
                unsigned byte = (unsigned)(row * 256 + (c32 * 32 + lk) * 2);
                byte ^= (unsigned)((row & 7) << 4);
                bb[i] = *(const short8*)((const char*)Bl + byte);
            }
#pragma unroll
            for (int i = 0; i < 2; ++i)
#pragma unroll
                for (int j = 0; j < 4; ++j)
                    acc[i][j] = __builtin_amdgcn_mfma_f32_16x16x32_bf16(
                        a[i], bb[j], acc[i][j], 0, 0, 0);
        }
    }

    // ---- epilogue: bias + store (col = o = lane&15, rows = 4 consecutive wo)
#pragma unroll
    for (int j = 0; j < 4; ++j) {
        int o = n_off + j * 16 + lr;
        float bs = bias[o];
#pragma unroll
        for (int i = 0; i < 2; ++i) {
            int wo = m_off + i * 16 + (lane >> 4) * 4;
            float4 vv;
            vv.x = acc[i][j][0] + bs;
            vv.y = acc[i][j][1] + bs;
            vv.z = acc[i][j][2] + bs;
            vv.w = acc[i][j][3] + bs;
            *(float4*)(out + (size_t)(b * OO + o) * (HH * WW) + ho * 64 + wo) = vv;
        }
    }
}

extern "C" void kernel_launch(void* const* d_in, const int* in_sizes, int n_in,
                              void* d_out, int out_size, void* d_ws, size_t ws_size,
                              hipStream_t stream) {
    const float* inp    = (const float*)d_in[0];
    const float* offset = (const float*)d_in[1];
    const float* mask   = (const float*)d_in[2];
    const float* weight = (const float*)d_in[3];
    const float* bias   = (const float*)d_in[4];
    float* out = (float*)d_out;

    float* inhwc = (float*)d_ws;
    unsigned short* wbf =
        (unsigned short*)((char*)d_ws + (size_t)BB * HH * WW * CC * sizeof(float));

    transpose_nchw_nhwc<<<dim3(128, 4, 8), 256, 0, stream>>>(inp, inhwc);
    prep_weight<<<dim3((KT * OO * CC + 255) / 256), 256, 0, stream>>>(weight, wbf);
    deform_main<<<dim3(BB * HH), 256, 0, stream>>>(inhwc, wbf, offset, mask, bias, out);
}

// Round 4
// 93.695 us; speedup vs baseline: 1.2491x; 1.2491x over previous
//
#include <hip/hip_runtime.h>

#define BB 8
#define CC 128
#define HH 64
#define WW 64
#define OO 128
#define KT 9

typedef __attribute__((ext_vector_type(8))) _Float16 half8;
typedef __attribute__((ext_vector_type(8))) short short8;
typedef __attribute__((ext_vector_type(8))) unsigned short ushort8;
typedef __attribute__((ext_vector_type(4))) float f32x4;

__device__ inline unsigned short f2bf(float f) {
    union { float f; unsigned int u; } x; x.f = f;
    unsigned int u = x.u;
    unsigned int r = u + 0x7fff + ((u >> 16) & 1);
    return (unsigned short)(r >> 16);
}

// ---- prep 1: NCHW f32 -> NHWC f16 ----
__global__ __launch_bounds__(256) void prep_input(
    const float* __restrict__ in, _Float16* __restrict__ out) {
    __shared__ float t[CC][33];
    int b = blockIdx.y;
    int s0 = blockIdx.x * 32;
    int s = threadIdx.x & 31;
    int c0 = threadIdx.x >> 5;  // 0..7
    const float* ip = in + (size_t)b * CC * HH * WW;
#pragma unroll
    for (int c = 0; c < CC; c += 8)
        t[c + c0][s] = ip[(size_t)(c + c0) * (HH * WW) + s0 + s];
    __syncthreads();
    int ws = threadIdx.x >> 3;        // 0..31 spatial
    int cg = (threadIdx.x & 7) * 16;  // channel group of 16
    _Float16 v[16];
#pragma unroll
    for (int i = 0; i < 16; ++i) v[i] = (_Float16)t[cg + i][ws];
    _Float16* op = out + ((size_t)(b * HH * WW) + s0 + ws) * CC + cg;
    *(half8*)op = *(half8*)&v[0];
    *(half8*)(op + 8) = *(half8*)&v[8];
}

// ---- prep 2 (round-1 proven): weight (O,C,3,3) f32 -> wbf[k][o][c] bf16 ----
__global__ __launch_bounds__(256) void prep_weight(
    const float* __restrict__ w, unsigned short* __restrict__ wbf) {
    int i = blockIdx.x * 256 + threadIdx.x;
    if (i >= KT * OO * CC) return;
    int k = i / (OO * CC);
    int r = i % (OO * CC);
    int o = r >> 7, c = r & 127;
    wbf[i] = f2bf(w[o * (CC * KT) + c * KT + k]);
}

// ---- main ----
struct Gather {
    half8 g[8];                 // 4 corners x 16ch (2x half8 each), f16
    float w00, w01, w10, w11;   // f32 bilinear*mask weights
};

__device__ __forceinline__ void sample_issue(
    const _Float16* __restrict__ base, int ho, int wo, int cs, int k,
    float oy, float ox, float mm, Gather& G) {
    int kh = k / 3, kw = k % 3;
    float py = (float)(ho - 1 + kh) + oy;
    float px = (float)(wo - 1 + kw) + ox;
    float fy = floorf(py), fx = floorf(px);
    float wy1 = py - fy, wx1 = px - fx;
    float wy0 = 1.f - wy1, wx0 = 1.f - wx1;
    int y0 = (int)fy, x0 = (int)fx;
    int y1 = y0 + 1, x1 = x0 + 1;
    bool vy0 = (y0 >= 0) & (y0 < HH);
    bool vy1 = (y1 >= 0) & (y1 < HH);
    bool vx0 = (x0 >= 0) & (x0 < WW);
    bool vx1 = (x1 >= 0) & (x1 < WW);
    G.w00 = (vy0 & vx0) ? wy0 * wx0 * mm : 0.f;
    G.w01 = (vy0 & vx1) ? wy0 * wx1 * mm : 0.f;
    G.w10 = (vy1 & vx0) ? wy1 * wx0 * mm : 0.f;
    G.w11 = (vy1 & vx1) ? wy1 * wx1 * mm : 0.f;
    int y0c = min(max(y0, 0), HH - 1), y1c = min(max(y1, 0), HH - 1);
    int x0c = min(max(x0, 0), WW - 1), x1c = min(max(x1, 0), WW - 1);
    const _Float16* p00 = base + (size_t)(y0c * WW + x0c) * CC + cs;
    const _Float16* p01 = base + (size_t)(y0c * WW + x1c) * CC + cs;
    const _Float16* p10 = base + (size_t)(y1c * WW + x0c) * CC + cs;
    const _Float16* p11 = base + (size_t)(y1c * WW + x1c) * CC + cs;
    G.g[0] = *(const half8*)p00;  G.g[1] = *(const half8*)(p00 + 8);
    G.g[2] = *(const half8*)p01;  G.g[3] = *(const half8*)(p01 + 8);
    G.g[4] = *(const half8*)p10;  G.g[5] = *(const half8*)(p10 + 8);
    G.g[6] = *(const half8*)p11;  G.g[7] = *(const half8*)(p11 + 8);
}

// f32 interpolation (round-1 numerics), f2bf, two 16-B stores with XOR swizzle
__device__ __forceinline__ void interp_write(
    char* lbuf, int px, int cs, const Gather& G) {
    ushort8 o0, o1;
#pragma unroll
    for (int j = 0; j < 8; ++j) {
        float s = G.w00 * (float)G.g[0][j] + G.w01 * (float)G.g[2][j] +
                  G.w10 * (float)G.g[4][j] + G.w11 * (float)G.g[6][j];
        o0[j] = f2bf(s);
    }
#pragma unroll
    for (int j = 0; j < 8; ++j) {
        float s = G.w00 * (float)G.g[1][j] + G.w01 * (float)G.g[3][j] +
                  G.w10 * (float)G.g[5][j] + G.w11 * (float)G.g[7][j];
        o1[j] = f2bf(s);
    }
    unsigned by = (unsigned)(px * 256 + cs * 2);
    unsigned sw = (unsigned)((px & 7) << 4);
    *(ushort8*)(lbuf + (by ^ sw)) = o0;
    *(ushort8*)(lbuf + ((by + 16) ^ sw)) = o1;
}

__global__ __launch_bounds__(256, 2) void deform_main(
    const _Float16* __restrict__ inh, const unsigned short* __restrict__ wbf,
    const float* __restrict__ offset, const float* __restrict__ mask,
    const float* __restrict__ bias, float* __restrict__ out) {
    __shared__ unsigned short Al[2][32 * 128];

    // XCD swizzle: each XCD owns exactly one batch image b.
    int hw = blockIdx.x;
    int lb = (hw & 7) * 128 + (hw >> 3);
    int wh = lb & 1;
    int ho = (lb >> 1) & 63;
    int b = lb >> 7;

    int tid = threadIdx.x;
    int wave = tid >> 6, lane = tid & 63;
    int lr = lane & 15, lk = (lane >> 4) * 8;
    int m_off = (wave >> 1) * 16;
    int n_off = (wave & 1) * 64;

    int px = tid >> 3;           // 0..31 pixel within block
    int cs = (tid & 7) * 16;     // channel start
    int wo = wh * 32 + px;

    const _Float16* base = inh + (size_t)b * HH * WW * CC;
    const float* offp = offset + (size_t)b * 18 * (HH * WW) + ho * WW + wo;
    const float* mskp = mask + (size_t)b * 9 * (HH * WW) + ho * WW + wo;

    f32x4 acc[4] = {};
    Gather G;

    // ---- prologue: tap 0 sample -> buf0; prefetch tap1 offsets
    {
        float oy = offp[0], ox = offp[HH * WW], mm = mskp[0];
        sample_issue(base, ho, wo, cs, 0, oy, ox, mm, G);
    }
    float oyN = offp[2 * HH * WW], oxN = offp[3 * HH * WW], mmN = mskp[HH * WW];
    interp_write((char*)Al[0], px, cs, G);
    __syncthreads();

    int buf = 0;
    for (int k = 0; k < KT; ++k) {
        // (1) B fragments for tap k: round-1-proven linear layout + address
        //     formula (lane holds o = n_off+i*16+lr, channels c32*32+lk..+7).
        const unsigned short* wk = wbf + (size_t)k * OO * CC;
        short8 Bf[16];
#pragma unroll
        for (int c32 = 0; c32 < 4; ++c32)
#pragma unroll
            for (int i = 0; i < 4; ++i) {
                int o = n_off + i * 16 + lr;
                Bf[c32 * 4 + i] =
                    *(const short8*)(wk + o * CC + c32 * 32 + lk);
            }

        // (2) issue gathers for tap k+1 (consumed after compute)
        if (k < KT - 1)
            sample_issue(base, ho, wo, cs, k + 1, oyN, oxN, mmN, G);
        // (2b) prefetch offsets two taps ahead
        if (k < KT - 2) {
            oyN = offp[(2 * k + 4) * (HH * WW)];
            oxN = offp[(2 * k + 5) * (HH * WW)];
            mmN = mskp[(k + 2) * (HH * WW)];
        }

        // (3) compute tap k from LDS buf (bf16 MFMA, round-1 proven)
#pragma unroll
        for (int c32 = 0; c32 < 4; ++c32) {
            int row = m_off + lr;
            unsigned rb = (unsigned)(row * 256 + (c32 * 32 + lk) * 2);
            rb ^= (unsigned)((row & 7) << 4);
            short8 a = *(const short8*)((const char*)Al[buf] + rb);
#pragma unroll
            for (int i = 0; i < 4; ++i)
                acc[i] = __builtin_amdgcn_mfma_f32_16x16x32_bf16(
                    a, Bf[c32 * 4 + i], acc[i], 0, 0, 0);
        }

        // (4) interp tap k+1, write other buffer
        if (k < KT - 1)
            interp_write((char*)Al[buf ^ 1], px, cs, G);
        __syncthreads();
        buf ^= 1;
    }

    // ---- epilogue: bias + store (o = n-tile + lane&15, px rows from C/D regs)
#pragma unroll
    for (int j = 0; j < 4; ++j) {
        int o = n_off + j * 16 + lr;
        float bs = bias[o];
        float4 v;
        v.x = acc[j][0] + bs;
        v.y = acc[j][1] + bs;
        v.z = acc[j][2] + bs;
        v.w = acc[j][3] + bs;
        int wo0 = wh * 32 + m_off + (lane >> 4) * 4;
        *(float4*)(out + (size_t)(b * OO + o) * (HH * WW) + ho * WW + wo0) = v;
    }
}

extern "C" void kernel_launch(void* const* d_in, const int* in_sizes, int n_in,
                              void* d_out, int out_size, void* d_ws, size_t ws_size,
                              hipStream_t stream) {
    const float* inp    = (const float*)d_in[0];
    const float* offset = (const float*)d_in[1];
    const float* mask   = (const float*)d_in[2];
    const float* weight = (const float*)d_in[3];
    const float* bias   = (const float*)d_in[4];
    float* out = (float*)d_out;

    _Float16* inh = (_Float16*)d_ws;  // 8 MB
    unsigned short* wbf =
        (unsigned short*)((char*)d_ws + (size_t)BB * HH * WW * CC * sizeof(_Float16));

    prep_input<<<dim3(128, 8), 256, 0, stream>>>(inp, inh);
    prep_weight<<<dim3((KT * OO * CC + 255) / 256), 256, 0, stream>>>(weight, wbf);
    deform_main<<<dim3(1024), 256, 0, stream>>>(inh, wbf, offset, mask, bias, out);
}

// Round 5
// 75.913 us; speedup vs baseline: 1.5417x; 1.2342x over previous
//
#include <hip/hip_runtime.h>

#define BB 8
#define CC 128
#define HH 64
#define WW 64
#define OO 128
#define KT 9
#define HWs (HH * WW)

typedef __attribute__((ext_vector_type(8))) _Float16 half8;
typedef __attribute__((ext_vector_type(8))) short short8;
typedef __attribute__((ext_vector_type(4))) float f32x4;

__device__ inline unsigned short f2bf(float f) {
    union { float f; unsigned int u; } x; x.f = f;
    unsigned int u = x.u;
    unsigned int r = u + 0x7fff + ((u >> 16) & 1);
    return (unsigned short)(r >> 16);
}

// ---- prep 1: NCHW f32 -> NHWC f16 (proven) ----
__global__ __launch_bounds__(256) void prep_input(
    const float* __restrict__ in, _Float16* __restrict__ out) {
    __shared__ float t[CC][33];
    int b = blockIdx.y;
    int s0 = blockIdx.x * 32;
    int s = threadIdx.x & 31;
    int c0 = threadIdx.x >> 5;
    const float* ip = in + (size_t)b * CC * HWs;
#pragma unroll
    for (int c = 0; c < CC; c += 8)
        t[c + c0][s] = ip[(size_t)(c + c0) * HWs + s0 + s];
    __syncthreads();
    int ws = threadIdx.x >> 3;
    int cg = (threadIdx.x & 7) * 16;
    _Float16 v[16];
#pragma unroll
    for (int i = 0; i < 16; ++i) v[i] = (_Float16)t[cg + i][ws];
    _Float16* op = out + ((size_t)(b * HWs) + s0 + ws) * CC + cg;
    *(half8*)op = *(half8*)&v[0];
    *(half8*)(op + 8) = *(half8*)&v[8];
}

// ---- prep 2 (proven): weight (O,C,3,3) f32 -> wbf[k][o][c] bf16 ----
__global__ __launch_bounds__(256) void prep_weight(
    const float* __restrict__ w, unsigned short* __restrict__ wbf) {
    int i = blockIdx.x * 256 + threadIdx.x;
    if (i >= KT * OO * CC) return;
    int k = i / (OO * CC);
    int r = i % (OO * CC);
    int o = r >> 7, c = r & 127;
    wbf[i] = f2bf(w[o * (CC * KT) + c * KT + k]);
}

// ---- main ----
struct GatherR {
    half8 g[16];                // [corner][c32]: 4 corners x 4 chunks of 8 ch
    float w00, w01, w10, w11;   // bilinear*mask weights (f32, proven numerics)
};

__device__ __forceinline__ void sample_issue_reg(
    const _Float16* __restrict__ base, int ho, int wo, int lk, int k,
    float oy, float ox, float mm, GatherR& G) {
    int kh = k / 3, kw = k % 3;
    float py = (float)(ho - 1 + kh) + oy;
    float px = (float)(wo - 1 + kw) + ox;
    float fy = floorf(py), fx = floorf(px);
    float wy1 = py - fy, wx1 = px - fx;
    float wy0 = 1.f - wy1, wx0 = 1.f - wx1;
    int y0 = (int)fy, x0 = (int)fx;
    int y1 = y0 + 1, x1 = x0 + 1;
    bool vy0 = (y0 >= 0) & (y0 < HH);
    bool vy1 = (y1 >= 0) & (y1 < HH);
    bool vx0 = (x0 >= 0) & (x0 < WW);
    bool vx1 = (x1 >= 0) & (x1 < WW);
    G.w00 = (vy0 & vx0) ? wy0 * wx0 * mm : 0.f;
    G.w01 = (vy0 & vx1) ? wy0 * wx1 * mm : 0.f;
    G.w10 = (vy1 & vx0) ? wy1 * wx0 * mm : 0.f;
    G.w11 = (vy1 & vx1) ? wy1 * wx1 * mm : 0.f;
    int y0c = min(max(y0, 0), HH - 1), y1c = min(max(y1, 0), HH - 1);
    int x0c = min(max(x0, 0), WW - 1), x1c = min(max(x1, 0), WW - 1);
    const _Float16* p00 = base + (size_t)(y0c * WW + x0c) * CC + lk;
    const _Float16* p01 = base + (size_t)(y0c * WW + x1c) * CC + lk;
    const _Float16* p10 = base + (size_t)(y1c * WW + x0c) * CC + lk;
    const _Float16* p11 = base + (size_t)(y1c * WW + x1c) * CC + lk;
#pragma unroll
    for (int c = 0; c < 4; ++c) G.g[0 * 4 + c] = *(const half8*)(p00 + c * 32);
#pragma unroll
    for (int c = 0; c < 4; ++c) G.g[1 * 4 + c] = *(const half8*)(p01 + c * 32);
#pragma unroll
    for (int c = 0; c < 4; ++c) G.g[2 * 4 + c] = *(const half8*)(p10 + c * 32);
#pragma unroll
    for (int c = 0; c < 4; ++c) G.g[3 * 4 + c] = *(const half8*)(p11 + c * 32);
}

__global__ __launch_bounds__(256, 2) void deform_main(
    const _Float16* __restrict__ inh, const unsigned short* __restrict__ wbf,
    const float* __restrict__ offset, const float* __restrict__ mask,
    const float* __restrict__ bias, float* __restrict__ out) {
    __shared__ unsigned short Bl[2][OO * CC];  // 2 x 32 KB, XOR-swizzled rows

    // XCD swizzle: 512 blocks, each XCD owns one batch image b.
    int hw = blockIdx.x;
    int lb = (hw & 7) * 64 + (hw >> 3);
    int ho = lb & 63;
    int b = lb >> 6;

    int tid = threadIdx.x;
    int wave = tid >> 6, lane = tid & 63;
    int lr = lane & 15, lk = (lane >> 4) * 8;
    int wo = wave * 16 + lr;     // this lane's pixel (A-row)

    // B staging mapping: each thread stages half a B row (128 B)
    int o_s = tid >> 1;
    int cb = (tid & 1) * 64;

    const _Float16* base = inh + (size_t)b * HWs * CC;
    const float* offp = offset + (size_t)b * 18 * HWs + ho * WW + wo;
    const float* mskp = mask + (size_t)b * 9 * HWs + ho * WW + wo;

    f32x4 acc[8] = {};
    GatherR G;
    int4 breg[8];

    // ---- prologue ----
    // B(0) loads (issued first: oldest vmem)
    {
        const int4* bsrc = (const int4*)(wbf + (size_t)0 * OO * CC + o_s * CC + cb);
#pragma unroll
        for (int j = 0; j < 8; ++j) breg[j] = bsrc[j];
    }
    // offsets(0) + gathers(0)
    {
        float oy = offp[0], ox = offp[HWs], mm = mskp[0];
        sample_issue_reg(base, ho, wo, lk, 0, oy, ox, mm, G);
    }
    // offsets(1)
    float oyN = offp[2 * HWs], oxN = offp[3 * HWs], mmN = mskp[HWs];
    // write B(0) to LDS (waits only the 8 B loads; gathers stay in flight)
    {
        char* dst = (char*)Bl[0];
#pragma unroll
        for (int j = 0; j < 8; ++j) {
            unsigned byte = (unsigned)(o_s * 256 + (cb + j * 8) * 2);
            byte ^= (unsigned)((o_s & 7) << 4);
            *(int4*)(dst + byte) = breg[j];
        }
    }
    __syncthreads();

    for (int k = 0; k < KT; ++k) {
        // (1) interp tap k -> A fragments (consumes gathers issued last iter)
        short8 af[4];
#pragma unroll
        for (int c = 0; c < 4; ++c) {
#pragma unroll
            for (int j = 0; j < 8; ++j) {
                float s = G.w00 * (float)G.g[0 * 4 + c][j] +
                          G.w01 * (float)G.g[1 * 4 + c][j] +
                          G.w10 * (float)G.g[2 * 4 + c][j] +
                          G.w11 * (float)G.g[3 * 4 + c][j];
                af[c][j] = (short)f2bf(s);
            }
        }

        if (k < KT - 1) {
            // (2) issue B(k+1) loads first (so later waits don't drain gathers)
            const int4* bsrc =
                (const int4*)(wbf + (size_t)(k + 1) * OO * CC + o_s * CC + cb);
#pragma unroll
            for (int j = 0; j < 8; ++j) breg[j] = bsrc[j];
            // (3) issue gathers(k+1)
            sample_issue_reg(base, ho, wo, lk, k + 1, oyN, oxN, mmN, G);
            // (4) prefetch offsets(k+2)
            if (k < KT - 2) {
                oyN = offp[(2 * k + 4) * HWs];
                oxN = offp[(2 * k + 5) * HWs];
                mmN = mskp[(k + 2) * HWs];
            }
        }

        // (5) MFMA tap k: A from regs, B from LDS (proven swizzled layout)
#pragma unroll
        for (int c = 0; c < 4; ++c) {
#pragma unroll
            for (int n = 0; n < 8; ++n) {
                int o = n * 16 + lr;
                unsigned rb = (unsigned)(o * 256 + (c * 32 + lk) * 2);
                rb ^= (unsigned)((o & 7) << 4);
                short8 bf = *(const short8*)((const char*)Bl[k & 1] + rb);
                acc[n] = __builtin_amdgcn_mfma_f32_16x16x32_bf16(
                    af[c], bf, acc[n], 0, 0, 0);
            }
        }

        // (6) write B(k+1) into the other LDS buffer; barrier
        if (k < KT - 1) {
            char* dst = (char*)Bl[(k + 1) & 1];
#pragma unroll
            for (int j = 0; j < 8; ++j) {
                unsigned byte = (unsigned)(o_s * 256 + (cb + j * 8) * 2);
                byte ^= (unsigned)((o_s & 7) << 4);
                *(int4*)(dst + byte) = breg[j];
            }
            __syncthreads();
        }
    }

    // ---- epilogue: bias + store (col o = lane&15, rows = 4 consecutive wo)
#pragma unroll
    for (int n = 0; n < 8; ++n) {
        int o = n * 16 + lr;
        float bs = bias[o];
        float4 v;
        v.x = acc[n][0] + bs;
        v.y = acc[n][1] + bs;
        v.z = acc[n][2] + bs;
        v.w = acc[n][3] + bs;
        int wo0 = wave * 16 + (lane >> 4) * 4;
        *(float4*)(out + (size_t)(b * OO + o) * HWs + ho * WW + wo0) = v;
    }
}

extern "C" void kernel_launch(void* const* d_in, const int* in_sizes, int n_in,
                              void* d_out, int out_size, void* d_ws, size_t ws_size,
                              hipStream_t stream) {
    const float* inp    = (const float*)d_in[0];
    const float* offset = (const float*)d_in[1];
    const float* mask   = (const float*)d_in[2];
    const float* weight = (const float*)d_in[3];
    const float* bias   = (const float*)d_in[4];
    float* out = (float*)d_out;

    _Float16* inh = (_Float16*)d_ws;  // 8 MB
    unsigned short* wbf =
        (unsigned short*)((char*)d_ws + (size_t)BB * HWs * CC * sizeof(_Float16));

    prep_input<<<dim3(128, 8), 256, 0, stream>>>(inp, inh);
    prep_weight<<<dim3((KT * OO * CC + 255) / 256), 256, 0, stream>>>(weight, wbf);
    deform_main<<<dim3(512), 256, 0, stream>>>(inh, wbf, offset, mask, bias, out);
}